// Round 5
// baseline (366.821 us; speedup 1.0000x reference)
//
#include <hip/hip_runtime.h>

typedef __bf16 bf16x8 __attribute__((ext_vector_type(8)));
typedef float f32x4 __attribute__((ext_vector_type(4)));

__device__ __forceinline__ unsigned short f2bf(float f) {
    union { float f; unsigned u; } v; v.f = f;
    unsigned r = v.u + 0x7FFFu + ((v.u >> 16) & 1u);   // round-to-nearest-even
    return (unsigned short)(r >> 16);
}

// ---------------------------------------------------------------------------
// prep mega-kernel: ALL preprocessing in one dispatch.  (unchanged from R4)
// ---------------------------------------------------------------------------
__global__ __launch_bounds__(256) void prep_kernel(
    const float4* __restrict__ inputs4, uint2* __restrict__ InB16,
    float4* __restrict__ out4,
    const float* __restrict__ W0, const float* __restrict__ W1,
    unsigned short* __restrict__ D0, unsigned short* __restrict__ D1,
    const int* __restrict__ mask,
    int* __restrict__ cnt, int* __restrict__ padded,
    float4* __restrict__ rowsum4,
    const float* __restrict__ memory,
    unsigned short* __restrict__ MemG, unsigned short* __restrict__ MemGT)
{
    __shared__ float tile[32][33];
    __shared__ float tileG[32][132];
    __shared__ int wsum[4];
    __shared__ int kidx32[32];
    const int bid = blockIdx.x;
    const int t = threadIdx.x;

    if (bid < 1024) {
        // ---- gather (with local mask scan), deep-ILP version ----
        const int b = bid >> 5;          // batch
        const int jt = bid & 31;         // j-tile (32 rows)
        const int j0 = jt * 32;
        const int* m = mask + b * 1024;
        int v[4]; int s = 0;
#pragma unroll
        for (int e = 0; e < 4; e++) { v[e] = (m[t * 4 + e] != 0) ? 1 : 0; s += v[e]; }
        const int lane = t & 63, wv = t >> 6;
        int x = s;
#pragma unroll
        for (int off = 1; off < 64; off <<= 1) {
            int y = __shfl_up(x, off, 64);
            if (lane >= off) x += y;
        }
        if (lane == 63) wsum[wv] = x;
        __syncthreads();
        int base = 0;
        for (int w = 0; w < wv; w++) base += wsum[w];
        const int nb = wsum[0] + wsum[1] + wsum[2] + wsum[3];
        const int pb = (nb + 127) & ~127;
        if (j0 >= pb) return;            // block-uniform
        int pos = base + x - s;          // exclusive prefix
#pragma unroll
        for (int e = 0; e < 4; e++)
            if (v[e]) {
                int p = pos++;
                if (p >= j0 && p < j0 + 32) kidx32[p - j0] = t * 4 + e;
            }
        __syncthreads();

        const float4* src4 = (const float4*)(memory + (size_t)b * 1024 * 512);
        const int jj = t >> 3;           // 0..31 (row within tile)
        const int cq = t & 7;            // 0..7  (16-float column chunk)
        const bool live = (j0 + jj) < nb;
        const int krow = live ? kidx32[jj] : 0;

        float4 vv[4][4];
        if (live) {
            const float4* rp = src4 + (size_t)krow * 128 + cq * 4;
#pragma unroll
            for (int c = 0; c < 4; c++)
#pragma unroll
                for (int i = 0; i < 4; i++) vv[c][i] = rp[c * 32 + i];
        } else {
#pragma unroll
            for (int c = 0; c < 4; c++)
#pragma unroll
                for (int i = 0; i < 4; i++) vv[c][i] = float4{0.f, 0.f, 0.f, 0.f};
        }

        unsigned short* mg = MemG + (size_t)b * 1024 * 512 + (size_t)(j0 + jj) * 512;
#pragma unroll
        for (int c = 0; c < 4; c++) {
            union { unsigned short u[16]; uint4 q[2]; } pk;
#pragma unroll
            for (int i = 0; i < 4; i++) {
                pk.u[i * 4 + 0] = f2bf(vv[c][i].x); pk.u[i * 4 + 1] = f2bf(vv[c][i].y);
                pk.u[i * 4 + 2] = f2bf(vv[c][i].z); pk.u[i * 4 + 3] = f2bf(vv[c][i].w);
            }
            *(uint4*)&mg[c * 128 + cq * 16] = pk.q[0];
            *(uint4*)&mg[c * 128 + cq * 16 + 8] = pk.q[1];
        }

        const int dd = t >> 1;           // 0..127 (d within chunk)
        const int jh = (t & 1) * 16;     // j half
        unsigned short* gtb = MemGT + (size_t)b * 512 * 1024 + j0 + jh;
#pragma unroll
        for (int c = 0; c < 4; c++) {
#pragma unroll
            for (int i = 0; i < 4; i++)
                *(float4*)&tileG[jj][cq * 16 + i * 4] = vv[c][i];
            __syncthreads();
            union { unsigned short u[16]; uint4 q[2]; } pt;
#pragma unroll
            for (int k = 0; k < 16; k++) pt.u[k] = f2bf(tileG[jh + k][dd]);
            unsigned short* gt = gtb + (size_t)(c * 128 + dd) * 1024;
            *(uint4*)&gt[0] = pt.q[0];
            *(uint4*)&gt[8] = pt.q[1];
            __syncthreads();
        }
    } else if (bid < 1056) {
        // ---- mask scan -> cnt/padded + rowsum zero ----
        const int b = bid - 1024;
        rowsum4[b * 256 + t] = float4{0.f, 0.f, 0.f, 0.f};
        const int* m = mask + b * 1024;
        int s = 0;
#pragma unroll
        for (int e = 0; e < 4; e++) s += (m[t * 4 + e] != 0) ? 1 : 0;
        const int lane = t & 63, wv = t >> 6;
        int x = s;
#pragma unroll
        for (int off = 1; off < 64; off <<= 1) {
            int y = __shfl_up(x, off, 64);
            if (lane >= off) x += y;
        }
        if (lane == 63) wsum[wv] = x;
        __syncthreads();
        if (t == 255) {
            int total = wsum[0] + wsum[1] + wsum[2] + wsum[3];
            cnt[b] = total;
            padded[b] = (total + 127) & ~127;
        }
    } else if (bid < 1568) {
        // ---- weight transpose ----
        const int tb = bid - 1056;
        const float* src = (tb >> 8) ? W1 : W0;
        unsigned short* dst = (tb >> 8) ? D1 : D0;
        const int rem = tb & 255;
        const int s0 = (rem & 15) * 32, d0 = (rem >> 4) * 32;
        const int tr = t >> 5, tc = t & 31;
#pragma unroll
        for (int i = 0; i < 4; i++)
            tile[tr + i * 8][tc] = src[(size_t)(s0 + tr + i * 8) * 512 + d0 + tc];
        __syncthreads();
#pragma unroll
        for (int i = 0; i < 4; i++)
            dst[(size_t)(d0 + tr + i * 8) * 512 + s0 + tc] = f2bf(tile[tc][tr + i * 8]);
    } else {
        // ---- fuse_inputs ----
        const int i = (bid - 1568) * 256 + t;   // 4194304 float4s total
        const int bq = i >> 7;
        const int d  = i & 127;
        float4 v = inputs4[i];
        out4[(size_t)bq * 256 + 128 + d] = v;
        union { unsigned short u[4]; uint2 p; } pk;
        pk.u[0] = f2bf(v.x); pk.u[1] = f2bf(v.y);
        pk.u[2] = f2bf(v.z); pk.u[3] = f2bf(v.w);
        InB16[i] = pk.p;
    }
}

// ---------------------------------------------------------------------------
// 128x128-tile, 4-wave, BK=64, 2-phase bf16 GEMM core, 64 KiB LDS
//   => 2 independent blocks per CU (decoupled barrier domains for latency
//      hiding).  Keeps: st-swizzle (T2), counted vmcnt(4) (T4), setprio (T5),
//      lgkmcnt(0)+sched_barrier fence (rule 18).
// CMODE 0: relu -> bf16
// CMODE 1: p = (col<nbv) ? exp(acc*scale) : 0 -> bf16; rs[row] += p (atomics)
// CMODE 2: acc / rs[row] -> fp32
// ---------------------------------------------------------------------------
template<int CMODE>
__device__ __forceinline__ void gemm_core(
    unsigned char* lds,
    const unsigned short* __restrict__ Ab, const unsigned short* __restrict__ Bb,
    void* __restrict__ Cb, float* __restrict__ rs, int nbv,
    int rowA, int rowB, int Kz, int lda, int ldb, int ldc, float scale)
{
    const int nt = Kz >> 6;                 // K-tiles of 64

    const int t = threadIdx.x;              // 0..255
    const int w = t >> 6;                   // wave 0..3
    const int lane = t & 63;
    const int wm = w >> 1;                  // 0..1 (M half)
    const int wn = w & 1;                   // 0..1 (N half)
    const int l15 = lane & 15;
    const int sx = (((lane >> 4) ^ ((l15 >> 1) & 3)) << 4);

    // staging: thread t covers linear bytes [t*16) and [t*16+4096) of each
    // 8 KiB half-tile (128 rows x 64 B); source pre-swizzled (same XOR).
    const int r0 = t >> 2;                          // row 0..63 (and +64)
    const int sl = (t & 3) ^ ((t >> 3) & 3);        // logical k-slot
    const unsigned short* aS0 = Ab + (size_t)(rowA + r0) * lda + sl * 8;
    const unsigned short* aS1 = aS0 + (size_t)64 * lda;
    const unsigned short* bS0 = Bb + (size_t)(rowB + r0) * ldb + sl * 8;
    const unsigned short* bS1 = bS0 + (size_t)64 * ldb;

    const int wofs = w * 1024;                      // wave-uniform dest base
    // LDS map: buf*32768 + {A: kh*8192 | B: 16384 + kh*8192}
    const int aRd = (wm * 64 + l15) * 64 + sx;
    const int bRd = 16384 + (wn * 64 + l15) * 64 + sx;

    f32x4 acc[4][4];
#pragma unroll
    for (int i = 0; i < 4; i++)
#pragma unroll
        for (int j = 0; j < 4; j++) acc[i][j] = f32x4{0.f, 0.f, 0.f, 0.f};

#define GLL(SRC, DOFS) __builtin_amdgcn_global_load_lds(                        \
        (const __attribute__((address_space(1))) void*)(SRC),                   \
        (__attribute__((address_space(3))) void*)&lds[DOFS], 16, 0, 0)
#define STAGEA(BUF, KH, KEL) do {                                               \
        GLL(aS0 + (KEL), (BUF) * 32768 + (KH) * 8192 + wofs);                   \
        GLL(aS1 + (KEL), (BUF) * 32768 + (KH) * 8192 + wofs + 4096); } while (0)
#define STAGEB(BUF, KH, KEL) do {                                               \
        GLL(bS0 + (KEL), (BUF) * 32768 + 16384 + (KH) * 8192 + wofs);           \
        GLL(bS1 + (KEL), (BUF) * 32768 + 16384 + (KH) * 8192 + wofs + 4096); } while (0)

    // prologue: tile 0 (klo A, klo B, khi A, khi B) -> 8 loads
    STAGEA(0, 0, 0); STAGEB(0, 0, 0); STAGEA(0, 1, 32); STAGEB(0, 1, 32);
    asm volatile("s_waitcnt vmcnt(4)" ::: "memory");   // klo landed; khi 4 outstanding
    __builtin_amdgcn_s_barrier();

    for (int tt = 0; tt < nt; ++tt) {
        const int cur = (tt & 1) * 32768;
        const int nxt = (tt & 1) ^ 1;
        const bool pf = (tt + 1) < nt;
        const int kn = (tt + 1) * 64;
        bf16x8 af[4], bfr[4];

        // ---- phase 0: klo, all 16 MFMA ----
#pragma unroll
        for (int i = 0; i < 4; i++) af[i]  = *(const bf16x8*)&lds[cur + aRd + i * 1024];
#pragma unroll
        for (int j = 0; j < 4; j++) bfr[j] = *(const bf16x8*)&lds[cur + bRd + j * 1024];
        if (pf) { STAGEA(nxt, 0, kn); STAGEB(nxt, 0, kn); }
        __builtin_amdgcn_s_barrier();
        asm volatile("s_waitcnt lgkmcnt(0)" ::: "memory");
        __builtin_amdgcn_sched_barrier(0);
        __builtin_amdgcn_s_setprio(1);
#pragma unroll
        for (int i = 0; i < 4; i++)
#pragma unroll
            for (int j = 0; j < 4; j++)
                acc[i][j] = __builtin_amdgcn_mfma_f32_16x16x32_bf16(af[i], bfr[j], acc[i][j], 0, 0, 0);
        __builtin_amdgcn_s_setprio(0);
        // khi(cur) must be resident before phase 1 reads.
        // outstanding (pf): [khi(cur) 4, klo(nxt) 4] -> vmcnt(4)
        if (pf) { asm volatile("s_waitcnt vmcnt(4)" ::: "memory"); }
        else    { asm volatile("s_waitcnt vmcnt(0)" ::: "memory"); }
        __builtin_amdgcn_s_barrier();

        // ---- phase 1: khi, all 16 MFMA ----
#pragma unroll
        for (int i = 0; i < 4; i++) af[i]  = *(const bf16x8*)&lds[cur + 8192 + aRd + i * 1024];
#pragma unroll
        for (int j = 0; j < 4; j++) bfr[j] = *(const bf16x8*)&lds[cur + 8192 + bRd + j * 1024];
        if (pf) { STAGEA(nxt, 1, kn + 32); STAGEB(nxt, 1, kn + 32); }
        __builtin_amdgcn_s_barrier();
        asm volatile("s_waitcnt lgkmcnt(0)" ::: "memory");
        __builtin_amdgcn_sched_barrier(0);
        __builtin_amdgcn_s_setprio(1);
#pragma unroll
        for (int i = 0; i < 4; i++)
#pragma unroll
            for (int j = 0; j < 4; j++)
                acc[i][j] = __builtin_amdgcn_mfma_f32_16x16x32_bf16(af[i], bfr[j], acc[i][j], 0, 0, 0);
        __builtin_amdgcn_s_setprio(0);
        // klo(nxt) must be resident before next phase 0.
        // outstanding: [klo(nxt) 4, khi(nxt) 4] -> vmcnt(4)
        if (pf) { asm volatile("s_waitcnt vmcnt(4)" ::: "memory"); }
        __builtin_amdgcn_s_barrier();
    }

#undef GLL
#undef STAGEA
#undef STAGEB

    // epilogue: C/D layout col=lane&15, row=(lane>>4)*4+reg
    const int orow = (lane >> 4) * 4;
    const int ocol = l15;

    if constexpr (CMODE == 0) {
        unsigned short* C = (unsigned short*)Cb;
#pragma unroll
        for (int mf = 0; mf < 4; mf++)
#pragma unroll
            for (int nf = 0; nf < 4; nf++) {
                const int col = rowB + wn * 64 + nf * 16 + ocol;
#pragma unroll
                for (int r = 0; r < 4; r++) {
                    const int rw = rowA + wm * 64 + mf * 16 + orow + r;
                    C[(size_t)rw * ldc + col] = f2bf(fmaxf(acc[mf][nf][r], 0.f));
                }
            }
    } else if constexpr (CMODE == 1) {
        unsigned short* C = (unsigned short*)Cb;
#pragma unroll
        for (int mf = 0; mf < 4; mf++) {
            float part[4] = {0.f, 0.f, 0.f, 0.f};
#pragma unroll
            for (int nf = 0; nf < 4; nf++) {
                const int col = rowB + wn * 64 + nf * 16 + ocol;
#pragma unroll
                for (int r = 0; r < 4; r++) {
                    float p = (col < nbv) ? __expf(acc[mf][nf][r] * scale) : 0.f;
                    part[r] += p;
                    const int rw = rowA + wm * 64 + mf * 16 + orow + r;
                    C[(size_t)rw * ldc + col] = f2bf(p);
                }
            }
#pragma unroll
            for (int r = 0; r < 4; r++) {
                float s = part[r];
                s += __shfl_xor(s, 1, 64);
                s += __shfl_xor(s, 2, 64);
                s += __shfl_xor(s, 4, 64);
                s += __shfl_xor(s, 8, 64);
                if (ocol == 0)
                    atomicAdd(&rs[rowA + wm * 64 + mf * 16 + orow + r], s);
            }
        }
    } else {  // CMODE == 2
        float* C = (float*)Cb;
#pragma unroll
        for (int mf = 0; mf < 4; mf++) {
            float inv[4];
#pragma unroll
            for (int r = 0; r < 4; r++)
                inv[r] = 1.0f / rs[rowA + wm * 64 + mf * 16 + orow + r];
#pragma unroll
            for (int nf = 0; nf < 4; nf++) {
                const int col = rowB + wn * 64 + nf * 16 + ocol;
#pragma unroll
                for (int r = 0; r < 4; r++) {
                    const int rw = rowA + wm * 64 + mf * 16 + orow + r;
                    C[(size_t)rw * ldc + col] = acc[mf][nf][r] * inv[r];
                }
            }
        }
    }
}

// ---------------------------------------------------------------------------
// Merged projection GEMMs. 2048 blocks, XCD-clustered:
//   id -> xcd=id&7, u8=id>>3; y = xcd + 8*(u8>>2) in [0,512); x = u8&3
//   y<256 : Xq = relu(InB16 @ Wt_in^T), rowA = y*128
//   y>=256: Xm = relu(MemG @ Wt_mem^T), z=(y-256)>>3, rowA=((y-256)&7)*128
// ---------------------------------------------------------------------------
__global__ __launch_bounds__(256, 2) void gemm_proj_kernel(
    const unsigned short* __restrict__ InB16, const unsigned short* __restrict__ WtIn,
    unsigned short* __restrict__ Xq,
    const unsigned short* __restrict__ MemG, const unsigned short* __restrict__ WtMem,
    unsigned short* __restrict__ Xm, const int* __restrict__ padded)
{
    __shared__ __align__(16) unsigned char lds[65536];
    const int id = blockIdx.x;
    const int xcd = id & 7, u8 = id >> 3;
    const int y = xcd + 8 * (u8 >> 2);
    const int x = u8 & 3;
    const int rowB = x * 128;
    const unsigned short* A;
    const unsigned short* Bt;
    unsigned short* C;
    int rowA;
    if (y < 256) {
        A = InB16; Bt = WtIn; C = Xq; rowA = y * 128;
    } else {
        const int idx = y - 256;
        const int z = idx >> 3;
        rowA = (idx & 7) * 128;
        if (rowA >= padded[z]) return;
        A = MemG + (size_t)z * 524288;
        Bt = WtMem;
        C = Xm + (size_t)z * 524288;
    }
    gemm_core<0>(lds, A, Bt, (void*)C, nullptr, 0, rowA, rowB,
                 512, 512, 512, 512, 0.f);
}

// P = exp(Xq @ Xm^T * scale) masked; rowsum atomics.
// 2048 blocks: xcd=id&7, u=id>>3; z = xcd + 8*(u>>6); r=u&63; x=r&7; y=r>>3.
__global__ __launch_bounds__(256, 2) void gemm_p_kernel(
    const unsigned short* __restrict__ Xq, const unsigned short* __restrict__ Xm,
    unsigned short* __restrict__ P, const int* __restrict__ cnt,
    const int* __restrict__ padded, float* __restrict__ rowsum, float scale)
{
    __shared__ __align__(16) unsigned char lds[65536];
    const int id = blockIdx.x;
    const int xcd = id & 7, u = id >> 3;
    const int z = xcd + 8 * (u >> 6);
    const int r = u & 63;
    const int x = r & 7, y = r >> 3;
    const int rowB = x * 128;
    if (rowB >= padded[z]) return;
    gemm_core<1>(lds, Xq + (size_t)z * 524288, Xm + (size_t)z * 524288,
                 (void*)(P + (size_t)z * 1048576), rowsum + (size_t)z * 1024, cnt[z],
                 y * 128, rowB, 512, 512, 512, 1024, scale);
}

// context = (P @ MemGT^T) / rowsum -> fp32 out[..., 0:512]
// 1024 blocks: xcd=id&7, u=id>>3; z = xcd + 8*(u>>5); r=u&31; x=r&3; y=r>>2.
__global__ __launch_bounds__(256, 2) void gemm_ctx_kernel(
    const unsigned short* __restrict__ P, const unsigned short* __restrict__ MemGT,
    float* __restrict__ out, const int* __restrict__ padded, float* __restrict__ rowsum)
{
    __shared__ __align__(16) unsigned char lds[65536];
    const int id = blockIdx.x;
    const int xcd = id & 7, u = id >> 3;
    const int z = xcd + 8 * (u >> 5);
    const int r = u & 31;
    const int x = r & 3, y = r >> 2;
    gemm_core<2>(lds, P + (size_t)z * 1048576, MemGT + (size_t)z * 524288,
                 (void*)(out + (size_t)z * 1048576), rowsum + (size_t)z * 1024, 0,
                 y * 128, x * 128, padded[z],
                 1024, 1024, 1024, 1.f);
}

extern "C" void kernel_launch(void* const* d_in, const int* in_sizes, int n_in,
                              void* d_out, int out_size, void* d_ws, size_t ws_size,
                              hipStream_t stream)
{
    const float* inputs = (const float*)d_in[0];   // [32,1024,512]
    const float* memory = (const float*)d_in[1];   // [32,1024,512]
    const int*   mmask  = (const int*)d_in[2];     // [32,1024]
    const float* W_in   = (const float*)d_in[3];   // [512,512]
    const float* W_mem  = (const float*)d_in[4];   // [512,512]
    float* out = (float*)d_out;                    // [32,1024,1024]

    char* ws = (char*)d_ws;
    const unsigned long long MB = 1048576ull;
    unsigned short* Wt_in  = (unsigned short*)(ws);                   // 512 KiB
    unsigned short* Wt_mem = (unsigned short*)(ws + 524288);          // 512 KiB
    unsigned short* InB16  = (unsigned short*)(ws + 1 * MB);          // 32 MiB
    unsigned short* MemG   = (unsigned short*)(ws + 33 * MB);         // 32 MiB
    unsigned short* P      = (unsigned short*)(ws + 1 * MB);          // 64 MiB (alias over InB16+MemG)
    unsigned short* MemGT  = (unsigned short*)(ws + 65 * MB);         // 32 MiB
    unsigned short* Xq     = (unsigned short*)(ws + 97 * MB);         // 32 MiB
    unsigned short* Xm     = (unsigned short*)(ws + 129 * MB);        // 32 MiB
    float*          rowsum = (float*)(ws + 161 * MB);                 // 128 KiB
    int*            cntp   = (int*)(ws + 161 * MB + 262144);          // 128 B
    int*            padp   = (int*)(ws + 161 * MB + 262144 + 128);    // 128 B

    const float scale = 0.04419417382415922f;  // 1/sqrt(512)

    // 1. everything independent in one dispatch
    prep_kernel<<<17952, 256, 0, stream>>>(
        (const float4*)inputs, (uint2*)InB16, (float4*)out,
        W_in, W_mem, Wt_in, Wt_mem,
        mmask, cntp, padp, (float4*)rowsum,
        memory, MemG, MemGT);

    // 2. both projections (2 blocks/CU)
    gemm_proj_kernel<<<2048, 256, 0, stream>>>(
        InB16, Wt_in, Xq, MemG, Wt_mem, Xm, padp);

    // 3. P = exp(Xq @ Xm^T * scale) for col<cnt, else 0; rowsum atomics
    gemm_p_kernel<<<2048, 256, 0, stream>>>(
        Xq, Xm, P, cntp, padp, rowsum, scale);

    // 4. context = (P @ MemGT^T) / rowsum -> fp32 out[..., 0:512]
    gemm_ctx_kernel<<<1024, 256, 0, stream>>>(
        P, MemGT, out, padp, rowsum);
}